// Round 7
// baseline (87.992 us; speedup 1.0000x reference)
//
#include <hip/hip_runtime.h>

// 5x5 median, zero pad. Packed-f16: each lane computes 2 horizontally adjacent
// outputs via v_pk_min_f16 / v_pk_max_f16. Strip height V=4 (was 8): doubles
// wave count to 48/CU for latency hiding, at +8% row-sort amortization cost.
// Raw row loads are prefetched one PROC ahead of their sort+use.
// Correctness: fp16 conversion is monotone -> median(cvt(x)) == cvt(median(x));
// only error is fp16 rounding of the final median (measured absmax 7.8e-3,
// threshold 2.8e-2). Input is randn -> no NaN/inf concerns.

typedef __fp16 h2 __attribute__((ext_vector_type(2)));

#define MIN2(a, b) __builtin_elementwise_min((a), (b))
#define MAX2(a, b) __builtin_elementwise_max((a), (b))

__device__ __forceinline__ void cswap(h2& a, h2& b) {
    h2 lo = MIN2(a, b);
    h2 hi = MAX2(a, b);
    a = lo; b = hi;
}

#define SORT4 { cswap(v0,v1); cswap(v2,v3); cswap(v0,v2); cswap(v1,v3); cswap(v1,v2); }

// top-2 (sorted) of 5
#define COL_TOP2(x0,x1,x2,x3,x4,o3,o4) { \
    h2 lo01=MIN2(x0,x1), hi01=MAX2(x0,x1); \
    h2 lo23=MIN2(x2,x3), hi23=MAX2(x2,x3); \
    h2 mx4 = MAX2(hi01,hi23); \
    h2 s4  = MAX2(MIN2(hi01,hi23), MAX2(lo01,lo23)); \
    h2 hi  = MAX2(mx4, x4), lo = MIN2(mx4, x4); \
    (o4) = hi; (o3) = MAX2(s4, lo); }

// bottom-2 (sorted) of 5
#define COL_BOT2(x0,x1,x2,x3,x4,o0,o1) { \
    h2 lo01=MIN2(x0,x1), hi01=MAX2(x0,x1); \
    h2 lo23=MIN2(x2,x3), hi23=MAX2(x2,x3); \
    h2 mn4 = MIN2(lo01,lo23); \
    h2 s4  = MIN2(MAX2(lo01,lo23), MIN2(hi01,hi23)); \
    h2 lo  = MIN2(mn4, x4), hi = MAX2(mn4, x4); \
    (o0) = lo; (o1) = MIN2(s4, hi); }

#define COL_TOP3(a0,a1,a2,a3,a4,o2,o3,o4) { \
    h2 v0=a0,v1=a1,v2=a2,v3=a3,v4=a4; SORT4; \
    cswap(v3,v4); cswap(v2,v3); cswap(v1,v2); (o2)=v2; (o3)=v3; (o4)=v4; (void)v0; }

#define COL_MID3(a0,a1,a2,a3,a4,o1,o2,o3) { \
    h2 v0=a0,v1=a1,v2=a2,v3=a3,v4=a4; SORT4; \
    cswap(v3,v4); cswap(v2,v3); cswap(v1,v2); cswap(v0,v1); (o1)=v1; (o2)=v2; (o3)=v3; }

#define COL_BOT3(a0,a1,a2,a3,a4,o0,o1,o2) { \
    h2 v0=a0,v1=a1,v2=a2,v3=a3,v4=a4; SORT4; \
    cswap(v0,v4); cswap(v1,v4); cswap(v2,v4); (o0)=v0; (o1)=v1; (o2)=v2; (void)v3; }

// odd-even merge(2,3): sorted (a0<=a1) + (p0<=p1<=p2) -> sorted L0..L4
#define MERGE23(a0,a1,p0,p1,p2,L0,L1,L2,L3,L4) { \
    h2 e0 = MIN2(a0,p0), t = MAX2(a0,p0); \
    h2 e1 = MIN2(t,p2),  e2 = MAX2(t,p2); \
    h2 o0 = MIN2(a1,p1), o1 = MAX2(a1,p1); \
    (L0)=e0; (L1)=MIN2(o0,e1); (L2)=MAX2(o0,e1); (L3)=MIN2(o1,e2); (L4)=MAX2(o1,e2); }

__global__ __launch_bounds__(256) void median5_kernel(const float* __restrict__ img,
                                                      float* __restrict__ out)
{
    const int W = 512, H = 512;
    const int t  = blockIdx.x * 64 + threadIdx.x;   // pixel-pair index, 0..255
    const int x0 = t * 2;                           // even column
    const int ty = blockIdx.y * 4 + threadIdx.y;    // strip index, 0..127
    const int y0 = ty * 4;                          // strip top row (V=4)
    const int p  = blockIdx.z;                      // plane

    const float* __restrict__ base = img + ((size_t)p << 18);
    float* __restrict__ obase = out + ((size_t)p << 18) + x0;

    const bool okL = (x0 >= 2);        // raw[0] covers cols x0-2, x0-1
    const bool okR = (x0 + 3 < W);     // raw[2] covers cols x0+2, x0+3

    h2 r[5][5];  // ring of 5 sorted rows (each entry = {px0 val, px1 val})

    // raw (unsorted, fp32) prefetch slot for the next row
    float2 raw0, raw1, raw2;

#define LOAD_RAW(yy) do { \
    const int _y = (yy); \
    if ((unsigned)_y < (unsigned)H) { \
        const float* _rp = base + _y * W + x0; \
        raw0 = okL ? *(const float2*)(_rp - 2) : make_float2(0.f, 0.f); \
        raw1 = *(const float2*)(_rp); \
        raw2 = okR ? *(const float2*)(_rp + 2) : make_float2(0.f, 0.f); \
    } else { \
        raw0 = make_float2(0.f, 0.f); \
        raw1 = make_float2(0.f, 0.f); \
        raw2 = make_float2(0.f, 0.f); \
    } \
} while (0)

#define SORT_RAW(SL) do { \
    h2 v0 = __builtin_amdgcn_cvt_pkrtz(raw0.x, raw0.y); \
    h2 v1 = __builtin_amdgcn_cvt_pkrtz(raw0.y, raw1.x); \
    h2 v2 = __builtin_amdgcn_cvt_pkrtz(raw1.x, raw1.y); \
    h2 v3 = __builtin_amdgcn_cvt_pkrtz(raw1.y, raw2.x); \
    h2 v4 = __builtin_amdgcn_cvt_pkrtz(raw2.x, raw2.y); \
    SORT4; \
    cswap(v3,v4); cswap(v2,v3); cswap(v1,v2); cswap(v0,v1); \
    r[SL][0]=v0; r[SL][1]=v1; r[SL][2]=v2; r[SL][3]=v3; r[SL][4]=v4; \
} while (0)

    // preload rows y0-2 .. y0+1 into slots 0..3
    LOAD_RAW(y0 - 2); SORT_RAW(0);
    LOAD_RAW(y0 - 1); SORT_RAW(1);
    LOAD_RAW(y0 + 0); SORT_RAW(2);
    LOAD_RAW(y0 + 1); SORT_RAW(3);
    LOAD_RAW(y0 + 2);  // prefetch for PROC 0

// PROC i: consume prefetched raw -> slot RE, prefetch next (i<3), select, store.
#define PROC(i, RA, RB, RC, RD, RE) do { \
    SORT_RAW(RE); \
    if ((i) < 3) LOAD_RAW(y0 + (i) + 3); \
    h2 a0,a1, p0,p1,p2, mm0,mm1,mm2, q0,q1,q2, d0,d1; \
    COL_TOP2(r[RA][0], r[RB][0], r[RC][0], r[RD][0], r[RE][0], a0, a1); \
    COL_TOP3(r[RA][1], r[RB][1], r[RC][1], r[RD][1], r[RE][1], p0, p1, p2); \
    COL_MID3(r[RA][2], r[RB][2], r[RC][2], r[RD][2], r[RE][2], mm0, mm1, mm2); \
    COL_BOT3(r[RA][3], r[RB][3], r[RC][3], r[RD][3], r[RE][3], q0, q1, q2); \
    COL_BOT2(r[RA][4], r[RB][4], r[RC][4], r[RD][4], r[RE][4], d0, d1); \
    h2 L0,L1,L2,L3,L4, R0,R1,R2,R3,R4; \
    MERGE23(a0, a1, p0, p1, p2, L0, L1, L2, L3, L4); \
    MERGE23(d0, d1, q0, q1, q2, R0, R1, R2, R3, R4); \
    /* pruned odd-even merge(5,5): ranks 4..7 of L∪R */ \
    h2 u  = MAX2(L1,R1), v  = MIN2(L3,R3); \
    h2 O1 = MIN2(u,v),   O2 = MAX2(u,v); \
    h2 u2 = MAX2(L0,R0), v2 = MIN2(L4,R4); \
    h2 F1 = MIN2(u2,v2), F2 = MAX2(u2,v2); \
    h2 G0 = MIN2(L2,R2), G1 = MAX2(L2,R2); \
    h2 E2 = MAX2(G0,F1), E3 = MIN2(G1,F2); \
    h2 Sa = MIN2(O1,E2), Sb = MAX2(O1,E2); \
    h2 Sc = MIN2(O2,E3), Sd = MAX2(O2,E3); \
    /* 7th of S(10) ∪ M(3): split identity */ \
    h2 med = MIN2( MIN2(MAX2(Sa,mm2), MAX2(Sb,mm1)), \
                   MIN2(MAX2(Sc,mm0), Sd) ); \
    float2 o; \
    o.x = (float)med.x; \
    o.y = (float)med.y; \
    *reinterpret_cast<float2*>(obase + (y0 + (i)) * W) = o; \
} while (0)

    PROC(0, 0, 1, 2, 3, 4);
    PROC(1, 1, 2, 3, 4, 0);
    PROC(2, 2, 3, 4, 0, 1);
    PROC(3, 3, 4, 0, 1, 2);
}

extern "C" void kernel_launch(void* const* d_in, const int* in_sizes, int n_in,
                              void* d_out, int out_size, void* d_ws, size_t ws_size,
                              hipStream_t stream)
{
    const float* img = (const float*)d_in[0];
    float* out = (float*)d_out;

    dim3 block(64, 4, 1);
    dim3 grid(512 / 2 / 64, 512 / 4 / 4, 24);  // (4, 32, 24) = 3072 blocks
    median5_kernel<<<grid, block, 0, stream>>>(img, out);
}